// Round 4
// baseline (340.807 us; speedup 1.0000x reference)
//
#include <hip/hip_runtime.h>
#include <hip/hip_bf16.h>
#include <stdint.h>

#define E_N   30000
#define C_IN  128
#define C_OUT 256
#define B_N   4
#define KTAP  5
#define BN    64

typedef short bf16x8 __attribute__((ext_vector_type(8)));
typedef float f32x4  __attribute__((ext_vector_type(4)));

static __device__ __forceinline__ unsigned short f2bf(float f) {
    union { float f; uint32_t u; } v; v.f = f;
    uint32_t r = (v.u + 0x7FFFu + ((v.u >> 16) & 1u)) >> 16;
    return (unsigned short)r;
}
static __device__ __forceinline__ float bf2f(uint32_t h) {
    union { uint32_t u; float f; } v; v.u = h << 16;
    return v.f;
}

// sum and |diff| of two bf16x8 chunks (f32 math, round back to bf16)
static __device__ __forceinline__ void comb8(const uint4& u, const uint4& v,
                                             uint4& s, uint4& d) {
    const uint32_t* a = (const uint32_t*)&u;
    const uint32_t* b = (const uint32_t*)&v;
    uint32_t* so = (uint32_t*)&s;
    uint32_t* dr = (uint32_t*)&d;
#pragma unroll
    for (int i = 0; i < 4; ++i) {
        float x0 = bf2f(a[i] & 0xFFFFu), x1 = bf2f(a[i] >> 16);
        float y0 = bf2f(b[i] & 0xFFFFu), y1 = bf2f(b[i] >> 16);
        so[i] = (uint32_t)f2bf(x0 + y0) | ((uint32_t)f2bf(x1 + y1) << 16);
        dr[i] = (uint32_t)f2bf(fabsf(x0 - y0)) | ((uint32_t)f2bf(fabsf(x1 - y1)) << 16);
    }
}

// ---------------------------------------------------------------------------
// Pack conv_w [256][128][5] f32 -> bf16 A-fragments, K tap-major:
// kappa = tap*128 + c.  A-frag for mfma_f32_16x16x32_bf16:
// lane holds A[m = mt*16 + (lane&15)][k = s*32 + (lane>>4)*8 + j], j=0..7.
// Linear halfword index: ((s*16 + mt)*64 + lane)*8 + j,  s = tap*4 + cbi.
// ---------------------------------------------------------------------------
__global__ void pack_w_kernel(const float* __restrict__ w,
                              unsigned short* __restrict__ wp) {
    int tid = blockIdx.x * blockDim.x + threadIdx.x;   // 20480 threads total
    if (tid >= 20 * 16 * 64) return;
    int s    = tid >> 10;
    int mt   = (tid >> 6) & 15;
    int lane = tid & 63;
    int m    = mt * 16 + (lane & 15);
    int kb   = s * 32 + ((lane >> 4) & 3) * 8;
    uint32_t pv[4];
    for (int jj = 0; jj < 4; ++jj) {
        unsigned short lo, hi;
        {
            int kk = kb + 2 * jj;
            int t = kk >> 7, c = kk & 127;
            lo = f2bf(w[(m * C_IN + c) * KTAP + t]);
        }
        {
            int kk = kb + 2 * jj + 1;
            int t = kk >> 7, c = kk & 127;
            hi = f2bf(w[(m * C_IN + c) * KTAP + t]);
        }
        pv[jj] = (uint32_t)lo | ((uint32_t)hi << 16);
    }
    uint4 val; val.x = pv[0]; val.y = pv[1]; val.z = pv[2]; val.w = pv[3];
    *(uint4*)(wp + (size_t)tid * 8) = val;
}

// ---------------------------------------------------------------------------
// Transpose x [B][C][E] f32 -> xT [B][E][C] bf16 (coalesced gathers in GEMM).
// ---------------------------------------------------------------------------
__global__ void transpose_kernel(const float* __restrict__ x,
                                 unsigned short* __restrict__ xT) {
    __shared__ float ld[C_IN][64 + 1];
    int b  = blockIdx.y;
    int e0 = blockIdx.x * 64;
    int t  = threadIdx.x;
    bool full = (e0 + 64 <= E_N);
    for (int pass = 0; pass < 8; ++pass) {
        int c  = pass * 16 + (t >> 4);
        int eo = (t & 15) * 4;
        if (full) {
            const float4 v = *(const float4*)(x + ((size_t)(b * C_IN + c) * E_N + e0 + eo));
            ld[c][eo] = v.x; ld[c][eo + 1] = v.y; ld[c][eo + 2] = v.z; ld[c][eo + 3] = v.w;
        } else {
            for (int i = 0; i < 4; ++i) {
                int e = e0 + eo + i;
                ld[c][eo + i] = (e < E_N) ? x[(size_t)(b * C_IN + c) * E_N + e] : 0.f;
            }
        }
    }
    __syncthreads();
    for (int pass = 0; pass < 4; ++pass) {
        int el = pass * 16 + (t >> 4);
        int c0 = (t & 15) * 8;
        int e  = e0 + el;
        if (e < E_N) {
            uint32_t pk[4];
            for (int i = 0; i < 4; ++i) {
                unsigned short lo = f2bf(ld[c0 + 2 * i][el]);
                unsigned short hi = f2bf(ld[c0 + 2 * i + 1][el]);
                pk[i] = (uint32_t)lo | ((uint32_t)hi << 16);
            }
            uint4 v; v.x = pk[0]; v.y = pk[1]; v.z = pk[2]; v.w = pk[3];
            *(uint4*)(xT + (size_t)(b * E_N + e) * C_IN + c0) = v;
        }
    }
}

// ---------------------------------------------------------------------------
// Fused gather + tap-combine + GEMM, K-HALF-SPLIT LDS for 3 blocks/CU.
//
// Identical body to round 3 (which PASSED correctness; the 178us came from
// amdgpu_waves_per_eu(6) crushing the allocator to 40 VGPR -> 280 MB scratch
// spill, visible as FETCH 207 MB / WRITE 403 MB).  Allocator control fixed:
// __launch_bounds__(512, 6) = min 6 waves/EU -> VGPR cap 512/6 ~= 85, which
// comfortably fits the ~62-75 live registers (acc 32 + g[5] 20 + addrs).
// 40 KB LDS + <=85 VGPR -> 3 blocks/CU (24 waves) vs round-0's 2 (16 waves):
// +50% independent wave streams to hide the L2 weight-load and gather
// latency that rounds 0-2 showed is the binding constraint (all pipes <27%).
// ---------------------------------------------------------------------------
__launch_bounds__(512, 6)
__global__ void mesh_gemm(const unsigned short* __restrict__ wp,
                          const unsigned short* __restrict__ xT,
                          const int* __restrict__ ne,
                          const float* __restrict__ bias,
                          float* __restrict__ out) {
    __shared__ uint4 gbuf[KTAP][BN][8];   // 40,960 B (XOR-swizzled chunks)

    const int tid  = threadIdx.x;
    const int lane = tid & 63;
    const int wave = tid >> 6;
    const int e0   = blockIdx.x * BN;
    const int b0   = blockIdx.y * 2;

    // gather role: 8 threads/edge, each owns ONE 16B chunk per half
    const int col = tid >> 3;
    const int ci  = tid & 7;
    const int cs  = ci ^ (col & 7);
    int eg = e0 + col; if (eg >= E_N) eg = E_N - 1;

    const unsigned short* xb0 = xT + (size_t)b0 * E_N * C_IN;
    const unsigned short* xb1 = xb0 + (size_t)E_N * C_IN;

    // MFMA-role constants
    const uint4* wp16 = (const uint4*)wp;
    const int nl = lane & 15;
    const int kq = lane >> 4;

    // ---------------- helpers ----------------
    auto gather5 = [&](const unsigned short* xb, const int4& nb, int h, uint4* g) {
        const int off = ci + (h << 3);          // chunk within 16-chunk row
        g[0] = ((const uint4*)(xb + (size_t)eg   * C_IN))[off];
        g[1] = ((const uint4*)(xb + (size_t)nb.x * C_IN))[off];
        g[2] = ((const uint4*)(xb + (size_t)nb.y * C_IN))[off];
        g[3] = ((const uint4*)(xb + (size_t)nb.z * C_IN))[off];
        g[4] = ((const uint4*)(xb + (size_t)nb.w * C_IN))[off];
    };
    auto combineStore5 = [&](const uint4* g) {
        uint4 s, d;
        gbuf[0][col][cs] = g[0];
        comb8(g[1], g[3], s, d); gbuf[1][col][cs] = s; gbuf[3][col][cs] = d;
        comb8(g[2], g[4], s, d); gbuf[2][col][cs] = s; gbuf[4][col][cs] = d;
    };
    auto mfmaHalf = [&](int h, f32x4 (&acc)[2][4]) {
        __builtin_amdgcn_s_setprio(1);
#pragma unroll 4
        for (int p = 0; p < 10; ++p) {
            const int tap = p >> 1, cbi2 = p & 1;
            const int s = tap * 4 + (h << 1) + cbi2;
            uint4 w0 = wp16[(s * 16 + wave * 2 + 0) * 64 + lane];
            uint4 w1 = wp16[(s * 16 + wave * 2 + 1) * 64 + lane];
            bf16x8 af0 = *(bf16x8*)&w0;
            bf16x8 af1 = *(bf16x8*)&w1;
#pragma unroll
            for (int nt = 0; nt < 4; ++nt) {
                uint4 bv = gbuf[tap][nt * 16 + nl][((cbi2 << 2) + kq) ^ (nl & 7)];
                bf16x8 bf = *(bf16x8*)&bv;
                acc[0][nt] = __builtin_amdgcn_mfma_f32_16x16x32_bf16(af0, bf, acc[0][nt], 0, 0, 0);
                acc[1][nt] = __builtin_amdgcn_mfma_f32_16x16x32_bf16(af1, bf, acc[1][nt], 0, 0, 0);
            }
        }
        __builtin_amdgcn_s_setprio(0);
    };
    auto storeOut = [&](int b, f32x4 (&acc)[2][4]) {
        float* outb = out + (size_t)b * C_OUT * E_N;
#pragma unroll
        for (int mt = 0; mt < 2; ++mt) {
            const int ob = (wave * 2 + mt) * 16 + kq * 4;
#pragma unroll
            for (int r = 0; r < 4; ++r) {
                const int o = ob + r;
                const float bv = bias[o];       // transient L2-hit load
#pragma unroll
                for (int nt = 0; nt < 4; ++nt) {
                    const int e = e0 + nt * 16 + nl;
                    if (e < E_N)
                        outb[(size_t)o * E_N + e] = acc[mt][nt][r] + bv;
                }
            }
        }
    };

    // ---------------- pipeline ----------------
    f32x4 acc[2][4];
    uint4 g[5];

    const int4 nb0 = *(const int4*)(ne + ((size_t)b0 * E_N + eg) * 4);

    gather5(xb0, nb0, 0, g);
    combineStore5(g);
    __syncthreads();                          // b0h0 staged

    const int4 nb1 = *(const int4*)(ne + ((size_t)(b0 + 1) * E_N + eg) * 4);
    gather5(xb0, nb0, 1, g);                  // in flight under MFMA(b0h0)
#pragma unroll
    for (int mt = 0; mt < 2; ++mt)
#pragma unroll
        for (int nt = 0; nt < 4; ++nt)
            acc[mt][nt] = (f32x4){0.f, 0.f, 0.f, 0.f};
    mfmaHalf(0, acc);
    __syncthreads();                          // b0h0 reads done

    combineStore5(g);                         // stage b0h1
    __syncthreads();                          // b0h1 staged

    gather5(xb1, nb1, 0, g);                  // in flight under MFMA(b0h1)
    mfmaHalf(1, acc);
    storeOut(b0, acc);
    __syncthreads();                          // b0h1 reads done

    combineStore5(g);                         // stage b1h0
    __syncthreads();                          // b1h0 staged

    gather5(xb1, nb1, 1, g);                  // in flight under MFMA(b1h0)
#pragma unroll
    for (int mt = 0; mt < 2; ++mt)
#pragma unroll
        for (int nt = 0; nt < 4; ++nt)
            acc[mt][nt] = (f32x4){0.f, 0.f, 0.f, 0.f};
    mfmaHalf(0, acc);
    __syncthreads();                          // b1h0 reads done

    combineStore5(g);                         // stage b1h1
    __syncthreads();                          // b1h1 staged

    mfmaHalf(1, acc);
    storeOut(b0 + 1, acc);
}

// ---------------------------------------------------------------------------
// Fallback (ws too small): direct fp32 compute, slow but correct.
// ---------------------------------------------------------------------------
__global__ void fallback_kernel(const float* __restrict__ x,
                                const int* __restrict__ ne,
                                const float* __restrict__ w,
                                const float* __restrict__ bias,
                                float* __restrict__ out) {
    size_t id = (size_t)blockIdx.x * blockDim.x + threadIdx.x;
    if (id >= (size_t)B_N * C_OUT * E_N) return;
    int e = (int)(id % E_N);
    int o = (int)((id / E_N) % C_OUT);
    int b = (int)(id / ((size_t)E_N * C_OUT));
    const int4 nb = *(const int4*)(ne + ((size_t)b * E_N + e) * 4);
    float acc = bias[o];
    for (int c = 0; c < C_IN; ++c) {
        const float* xb = x + (size_t)(b * C_IN + c) * E_N;
        float s0 = xb[e];
        float x1 = xb[nb.x], x2 = xb[nb.y], x3 = xb[nb.z], x4 = xb[nb.w];
        const float* wo = w + (size_t)(o * C_IN + c) * KTAP;
        acc += wo[0] * s0
             + wo[1] * (x1 + x3)
             + wo[2] * (x2 + x4)
             + wo[3] * fabsf(x1 - x3)
             + wo[4] * fabsf(x2 - x4);
    }
    out[id] = acc;
}

extern "C" void kernel_launch(void* const* d_in, const int* in_sizes, int n_in,
                              void* d_out, int out_size, void* d_ws, size_t ws_size,
                              hipStream_t stream) {
    const float* x      = (const float*)d_in[0];
    const int*   ne_idx = (const int*)d_in[1];
    const float* conv_w = (const float*)d_in[2];
    const float* conv_b = (const float*)d_in[3];
    float* out = (float*)d_out;

    const size_t xT_off = 512 * 1024;
    const size_t need   = xT_off + (size_t)B_N * E_N * C_IN * 2;  // ~31.2 MB

    if (ws_size < need) {
        size_t total = (size_t)B_N * C_OUT * E_N;
        int blocks = (int)((total + 255) / 256);
        fallback_kernel<<<blocks, 256, 0, stream>>>(x, ne_idx, conv_w, conv_b, out);
        return;
    }

    unsigned short* wp = (unsigned short*)d_ws;
    unsigned short* xT = (unsigned short*)((char*)d_ws + xT_off);

    pack_w_kernel<<<80, 256, 0, stream>>>(conv_w, wp);
    dim3 tg((E_N + 63) / 64, B_N);
    transpose_kernel<<<tg, 256, 0, stream>>>(x, xT);
    dim3 gg((E_N + BN - 1) / BN, B_N / 2);
    mesh_gemm<<<gg, 512, 0, stream>>>(wp, xT, ne_idx, conv_b, out);
}

// Round 5
// 233.513 us; speedup vs baseline: 1.4595x; 1.4595x over previous
//
#include <hip/hip_runtime.h>
#include <hip/hip_bf16.h>
#include <stdint.h>

#define E_N   30000
#define C_IN  128
#define C_OUT 256
#define B_N   4
#define KTAP  5
#define BN    64

typedef short bf16x8 __attribute__((ext_vector_type(8)));
typedef float f32x4  __attribute__((ext_vector_type(4)));

static __device__ __forceinline__ unsigned short f2bf(float f) {
    union { float f; uint32_t u; } v; v.f = f;
    uint32_t r = (v.u + 0x7FFFu + ((v.u >> 16) & 1u)) >> 16;
    return (unsigned short)r;
}
static __device__ __forceinline__ float bf2f(uint32_t h) {
    union { uint32_t u; float f; } v; v.u = h << 16;
    return v.f;
}

// LDS-only workgroup barrier: waits for this wave's LDS ops (lgkmcnt) but
// does NOT drain in-flight global loads/stores (vmcnt) the way
// __syncthreads() does (hipcc emits s_waitcnt vmcnt(0) before s_barrier).
// Output stores are never re-read and gather-load consumers get their own
// compiler-inserted vmcnt waits by register dataflow, so skipping the drain
// is safe here and keeps ~64 KB of stores + 10 gather loads in flight
// across each phase boundary (T4: never vmcnt(0) inside the loop).
static __device__ __forceinline__ void ldsBarrier() {
    __builtin_amdgcn_sched_barrier(0);
    asm volatile("s_waitcnt lgkmcnt(0)" ::: "memory");
    __builtin_amdgcn_s_barrier();
    __builtin_amdgcn_sched_barrier(0);
}

// sum and |diff| of two bf16x8 chunks (f32 math, round back to bf16)
static __device__ __forceinline__ void comb8(const uint4& u, const uint4& v,
                                             uint4& s, uint4& d) {
    const uint32_t* a = (const uint32_t*)&u;
    const uint32_t* b = (const uint32_t*)&v;
    uint32_t* so = (uint32_t*)&s;
    uint32_t* dr = (uint32_t*)&d;
#pragma unroll
    for (int i = 0; i < 4; ++i) {
        float x0 = bf2f(a[i] & 0xFFFFu), x1 = bf2f(a[i] >> 16);
        float y0 = bf2f(b[i] & 0xFFFFu), y1 = bf2f(b[i] >> 16);
        so[i] = (uint32_t)f2bf(x0 + y0) | ((uint32_t)f2bf(x1 + y1) << 16);
        dr[i] = (uint32_t)f2bf(fabsf(x0 - y0)) | ((uint32_t)f2bf(fabsf(x1 - y1)) << 16);
    }
}

// ---------------------------------------------------------------------------
// Pack conv_w [256][128][5] f32 -> bf16 A-fragments, K tap-major:
// kappa = tap*128 + c.  A-frag for mfma_f32_16x16x32_bf16:
// lane holds A[m = mt*16 + (lane&15)][k = s*32 + (lane>>4)*8 + j], j=0..7.
// Linear halfword index: ((s*16 + mt)*64 + lane)*8 + j,  s = tap*4 + cbi.
// ---------------------------------------------------------------------------
__global__ void pack_w_kernel(const float* __restrict__ w,
                              unsigned short* __restrict__ wp) {
    int tid = blockIdx.x * blockDim.x + threadIdx.x;   // 20480 threads total
    if (tid >= 20 * 16 * 64) return;
    int s    = tid >> 10;
    int mt   = (tid >> 6) & 15;
    int lane = tid & 63;
    int m    = mt * 16 + (lane & 15);
    int kb   = s * 32 + ((lane >> 4) & 3) * 8;
    uint32_t pv[4];
    for (int jj = 0; jj < 4; ++jj) {
        unsigned short lo, hi;
        {
            int kk = kb + 2 * jj;
            int t = kk >> 7, c = kk & 127;
            lo = f2bf(w[(m * C_IN + c) * KTAP + t]);
        }
        {
            int kk = kb + 2 * jj + 1;
            int t = kk >> 7, c = kk & 127;
            hi = f2bf(w[(m * C_IN + c) * KTAP + t]);
        }
        pv[jj] = (uint32_t)lo | ((uint32_t)hi << 16);
    }
    uint4 val; val.x = pv[0]; val.y = pv[1]; val.z = pv[2]; val.w = pv[3];
    *(uint4*)(wp + (size_t)tid * 8) = val;
}

// ---------------------------------------------------------------------------
// Transpose x [B][C][E] f32 -> xT [B][E][C] bf16 (coalesced gathers in GEMM).
// ---------------------------------------------------------------------------
__global__ void transpose_kernel(const float* __restrict__ x,
                                 unsigned short* __restrict__ xT) {
    __shared__ float ld[C_IN][64 + 1];
    int b  = blockIdx.y;
    int e0 = blockIdx.x * 64;
    int t  = threadIdx.x;
    bool full = (e0 + 64 <= E_N);
    for (int pass = 0; pass < 8; ++pass) {
        int c  = pass * 16 + (t >> 4);
        int eo = (t & 15) * 4;
        if (full) {
            const float4 v = *(const float4*)(x + ((size_t)(b * C_IN + c) * E_N + e0 + eo));
            ld[c][eo] = v.x; ld[c][eo + 1] = v.y; ld[c][eo + 2] = v.z; ld[c][eo + 3] = v.w;
        } else {
            for (int i = 0; i < 4; ++i) {
                int e = e0 + eo + i;
                ld[c][eo + i] = (e < E_N) ? x[(size_t)(b * C_IN + c) * E_N + e] : 0.f;
            }
        }
    }
    __syncthreads();
    for (int pass = 0; pass < 4; ++pass) {
        int el = pass * 16 + (t >> 4);
        int c0 = (t & 15) * 8;
        int e  = e0 + el;
        if (e < E_N) {
            uint32_t pk[4];
            for (int i = 0; i < 4; ++i) {
                unsigned short lo = f2bf(ld[c0 + 2 * i][el]);
                unsigned short hi = f2bf(ld[c0 + 2 * i + 1][el]);
                pk[i] = (uint32_t)lo | ((uint32_t)hi << 16);
            }
            uint4 v; v.x = pk[0]; v.y = pk[1]; v.z = pk[2]; v.w = pk[3];
            *(uint4*)(xT + (size_t)(b * E_N + e) * C_IN + c0) = v;
        }
    }
}

// ---------------------------------------------------------------------------
// Fused gather + tap-combine + GEMM, batch-pair software pipeline.
// EXACT round-0 structure (88.7 us, VGPR 64, 2 blocks/CU) with ONE change:
// the three __syncthreads() are now LDS-only barriers (no vmcnt(0) drain).
// Rationale: R0 counters showed every pipe <=26% busy -- the classic
// 2-phase stage->drain->MFMA structural stall (m233).  __syncthreads'
// mandatory vmcnt(0) serialized the ~64 KB output-store drain and gather
// latency into every phase boundary; ldsBarrier keeps them in flight.
// ---------------------------------------------------------------------------
__launch_bounds__(512, 4)
__global__ void mesh_gemm(const unsigned short* __restrict__ wp,
                          const unsigned short* __restrict__ xT,
                          const int* __restrict__ ne,
                          const float* __restrict__ bias,
                          float* __restrict__ out) {
    __shared__ uint4 gbuf[KTAP][BN][16];   // 81,920 B (XOR-swizzled chunks)

    const int e0   = blockIdx.x * BN;
    const int tid  = threadIdx.x;
    const int lane = tid & 63;
    const int wave = tid >> 6;
    const int b0   = blockIdx.y * 2;
    const int b1   = b0 + 1;

    // gather role: 8 threads/edge, each owns chunks ci and ci+8
    const int col = tid >> 3;
    const int ci  = tid & 7;
    int eg = e0 + col; if (eg >= E_N) eg = E_N - 1;

    const int4 nb0 = *(const int4*)(ne + ((size_t)b0 * E_N + eg) * 4);
    const int4 nb1 = *(const int4*)(ne + ((size_t)b1 * E_N + eg) * 4);

    const int sw = col & 15;
    const int cl = ci ^ sw;
    const int ch = (ci + 8) ^ sw;

    // MFMA-role constants
    const uint4* wp16 = (const uint4*)wp;
    const int nl   = lane & 15;
    const int kq   = lane >> 4;
    const int quad = kq;

    // hoist bias
    float bvl[2][4];
#pragma unroll
    for (int mt = 0; mt < 2; ++mt)
#pragma unroll
        for (int r = 0; r < 4; ++r)
            bvl[mt][r] = bias[(wave * 2 + mt) * 16 + quad * 4 + r];

    // ---------------- gather helpers ----------------
    auto gather10 = [&](int b, const int4& nb, uint4* g) {
        const unsigned short* xb = xT + (size_t)b * E_N * C_IN;
        const uint4* r0 = (const uint4*)(xb + (size_t)eg   * C_IN) + ci;
        const uint4* r1 = (const uint4*)(xb + (size_t)nb.x * C_IN) + ci;
        const uint4* r2 = (const uint4*)(xb + (size_t)nb.y * C_IN) + ci;
        const uint4* r3 = (const uint4*)(xb + (size_t)nb.z * C_IN) + ci;
        const uint4* r4 = (const uint4*)(xb + (size_t)nb.w * C_IN) + ci;
        g[0] = r0[0]; g[1] = r1[0]; g[2] = r2[0]; g[3] = r3[0]; g[4] = r4[0];
        g[5] = r0[8]; g[6] = r1[8]; g[7] = r2[8]; g[8] = r3[8]; g[9] = r4[8];
    };
    auto combineStore = [&](uint4* g) {
        uint4 s, d;
        gbuf[0][col][cl] = g[0];
        comb8(g[1], g[3], s, d); gbuf[1][col][cl] = s; gbuf[3][col][cl] = d;
        comb8(g[2], g[4], s, d); gbuf[2][col][cl] = s; gbuf[4][col][cl] = d;
        gbuf[0][col][ch] = g[5];
        comb8(g[6], g[8], s, d); gbuf[1][col][ch] = s; gbuf[3][col][ch] = d;
        comb8(g[7], g[9], s, d); gbuf[2][col][ch] = s; gbuf[4][col][ch] = d;
    };
    auto mfmaStore = [&](int b) {
        f32x4 acc[2][4];
#pragma unroll
        for (int mt = 0; mt < 2; ++mt)
#pragma unroll
            for (int nt = 0; nt < 4; ++nt)
                acc[mt][nt] = (f32x4){0.f, 0.f, 0.f, 0.f};
#pragma unroll 4
        for (int s = 0; s < 20; ++s) {
            const int tap = s >> 2, cbi = s & 3;
            uint4 w0 = wp16[(s * 16 + wave * 2 + 0) * 64 + lane];
            uint4 w1 = wp16[(s * 16 + wave * 2 + 1) * 64 + lane];
            bf16x8 af0 = *(bf16x8*)&w0;
            bf16x8 af1 = *(bf16x8*)&w1;
#pragma unroll
            for (int nt = 0; nt < 4; ++nt) {
                uint4 bv = gbuf[tap][nt * 16 + nl][((cbi << 2) + kq) ^ nl];
                bf16x8 bf = *(bf16x8*)&bv;
                acc[0][nt] = __builtin_amdgcn_mfma_f32_16x16x32_bf16(af0, bf, acc[0][nt], 0, 0, 0);
                acc[1][nt] = __builtin_amdgcn_mfma_f32_16x16x32_bf16(af1, bf, acc[1][nt], 0, 0, 0);
            }
        }
        // epilogue: C/D col = lane&15, row = quad*4 + r
#pragma unroll
        for (int mt = 0; mt < 2; ++mt) {
            const int ob = (wave * 2 + mt) * 16 + quad * 4;
#pragma unroll
            for (int r = 0; r < 4; ++r) {
                const int o = ob + r;
                const float bv = bvl[mt][r];
#pragma unroll
                for (int nt = 0; nt < 4; ++nt) {
                    const int e = e0 + nt * 16 + nl;
                    if (e < E_N)
                        out[((size_t)(b * C_OUT + o)) * E_N + e] = acc[mt][nt][r] + bv;
                }
            }
        }
    };

    // ---------------- pipeline ----------------
    uint4 ga[10];
    gather10(b0, nb0, ga);
    combineStore(ga);
    ldsBarrier();                          // A0: G(b0) visible (no vm drain)

    uint4 gb[10];
    gather10(b1, nb1, gb);                 // in flight under MFMA(b0)
    mfmaStore(b0);

    ldsBarrier();                          // B0: G(b0) reads done (stores stay in flight)
    combineStore(gb);
    ldsBarrier();                          // A1: G(b1) visible
    mfmaStore(b1);
}

// ---------------------------------------------------------------------------
// Fallback (ws too small): direct fp32 compute, slow but correct.
// ---------------------------------------------------------------------------
__global__ void fallback_kernel(const float* __restrict__ x,
                                const int* __restrict__ ne,
                                const float* __restrict__ w,
                                const float* __restrict__ bias,
                                float* __restrict__ out) {
    size_t id = (size_t)blockIdx.x * blockDim.x + threadIdx.x;
    if (id >= (size_t)B_N * C_OUT * E_N) return;
    int e = (int)(id % E_N);
    int o = (int)((id / E_N) % C_OUT);
    int b = (int)(id / ((size_t)E_N * C_OUT));
    const int4 nb = *(const int4*)(ne + ((size_t)b * E_N + e) * 4);
    float acc = bias[o];
    for (int c = 0; c < C_IN; ++c) {
        const float* xb = x + (size_t)(b * C_IN + c) * E_N;
        float s0 = xb[e];
        float x1 = xb[nb.x], x2 = xb[nb.y], x3 = xb[nb.z], x4 = xb[nb.w];
        const float* wo = w + (size_t)(o * C_IN + c) * KTAP;
        acc += wo[0] * s0
             + wo[1] * (x1 + x3)
             + wo[2] * (x2 + x4)
             + wo[3] * fabsf(x1 - x3)
             + wo[4] * fabsf(x2 - x4);
    }
    out[id] = acc;
}

extern "C" void kernel_launch(void* const* d_in, const int* in_sizes, int n_in,
                              void* d_out, int out_size, void* d_ws, size_t ws_size,
                              hipStream_t stream) {
    const float* x      = (const float*)d_in[0];
    const int*   ne_idx = (const int*)d_in[1];
    const float* conv_w = (const float*)d_in[2];
    const float* conv_b = (const float*)d_in[3];
    float* out = (float*)d_out;

    const size_t xT_off = 512 * 1024;
    const size_t need   = xT_off + (size_t)B_N * E_N * C_IN * 2;  // ~31.2 MB

    if (ws_size < need) {
        size_t total = (size_t)B_N * C_OUT * E_N;
        int blocks = (int)((total + 255) / 256);
        fallback_kernel<<<blocks, 256, 0, stream>>>(x, ne_idx, conv_w, conv_b, out);
        return;
    }

    unsigned short* wp = (unsigned short*)d_ws;
    unsigned short* xT = (unsigned short*)((char*)d_ws + xT_off);

    pack_w_kernel<<<80, 256, 0, stream>>>(conv_w, wp);
    dim3 tg((E_N + 63) / 64, B_N);
    transpose_kernel<<<tg, 256, 0, stream>>>(x, xT);
    dim3 gg((E_N + BN - 1) / BN, B_N / 2);
    mesh_gemm<<<gg, 512, 0, stream>>>(wp, xT, ne_idx, conv_b, out);
}

// Round 6
// 227.263 us; speedup vs baseline: 1.4996x; 1.0275x over previous
//
#include <hip/hip_runtime.h>
#include <hip/hip_bf16.h>
#include <stdint.h>

#define E_N   30000
#define C_IN  128
#define C_OUT 256
#define B_N   4
#define KTAP  5
#define BN    64
#define TP_X  469              // (E_N+63)/64 transpose tiles per batch

typedef short bf16x8 __attribute__((ext_vector_type(8)));
typedef float f32x4  __attribute__((ext_vector_type(4)));

static __device__ __forceinline__ unsigned short f2bf(float f) {
    union { float f; uint32_t u; } v; v.f = f;
    uint32_t r = (v.u + 0x7FFFu + ((v.u >> 16) & 1u)) >> 16;
    return (unsigned short)r;
}
static __device__ __forceinline__ float bf2f(uint32_t h) {
    union { uint32_t u; float f; } v; v.u = h << 16;
    return v.f;
}
// HW packed f32->bf16 (RNE, matches f2bf): lo16 = bf16(a), hi16 = bf16(b).
static __device__ __forceinline__ uint32_t pkbf(float a, float b) {
    uint32_t r;
    asm("v_cvt_pk_bf16_f32 %0, %1, %2" : "=v"(r) : "v"(a), "v"(b));
    return r;
}

// LDS-only workgroup barrier: waits for this wave's LDS ops (lgkmcnt) but
// does NOT drain in-flight global loads/stores (vmcnt) the way
// __syncthreads() does.  (Proven R5: mesh_gemm 88.7 -> <=77 us.)
static __device__ __forceinline__ void ldsBarrier() {
    __builtin_amdgcn_sched_barrier(0);
    asm volatile("s_waitcnt lgkmcnt(0)" ::: "memory");
    __builtin_amdgcn_s_barrier();
    __builtin_amdgcn_sched_barrier(0);
}

// sum and |diff| of two bf16x8 chunks (f32 math, round back to bf16)
static __device__ __forceinline__ void comb8(const uint4& u, const uint4& v,
                                             uint4& s, uint4& d) {
    const uint32_t* a = (const uint32_t*)&u;
    const uint32_t* b = (const uint32_t*)&v;
    uint32_t* so = (uint32_t*)&s;
    uint32_t* dr = (uint32_t*)&d;
#pragma unroll
    for (int i = 0; i < 4; ++i) {
        float x0 = bf2f(a[i] & 0xFFFFu), x1 = bf2f(a[i] >> 16);
        float y0 = bf2f(b[i] & 0xFFFFu), y1 = bf2f(b[i] >> 16);
        so[i] = (uint32_t)f2bf(x0 + y0) | ((uint32_t)f2bf(x1 + y1) << 16);
        dr[i] = (uint32_t)f2bf(fabsf(x0 - y0)) | ((uint32_t)f2bf(fabsf(x1 - y1)) << 16);
    }
}

// ---------------------------------------------------------------------------
// Fused prep kernel: blocks [0, TP_X*B_N) transpose x [B][C][E] f32 ->
// xT [B][E][C] bf16; blocks [TP_X*B_N, +80) pack conv_w -> A-fragments.
//
// Transpose redesign (R5 post-mortem: old version was instruction-bound,
// ~250 inst/thread, ~55-65 us inferred): pair channel rows (c, c+1) so one
// v_cvt_pk_bf16_f32 produces the final xT u32 cell; LDS [e][c-pair] layout
// stride 65 u32 -> read AND write banks 2-way max (free, m136); 16 ds_write
// + 16 ds_read + 16 cvt_pk per thread (~80 inst total).
//
// pack_w: lane holds A[m = mt*16 + (lane&15)][k = s*32 + (lane>>4)*8 + j];
// linear halfword index ((s*16 + mt)*64 + lane)*8 + j, s = tap*4 + cbi.
// ---------------------------------------------------------------------------
__global__ void prep_kernel(const float* __restrict__ x,
                            unsigned short* __restrict__ xT,
                            const float* __restrict__ w,
                            unsigned short* __restrict__ wp) {
    const int bid = blockIdx.x;
    const int t   = threadIdx.x;

    if (bid >= TP_X * B_N) {
        // ---------------- pack_w role ----------------
        int tid = (bid - TP_X * B_N) * 256 + t;        // [0, 20480)
        int s    = tid >> 10;
        int mt   = (tid >> 6) & 15;
        int lane = tid & 63;
        int m    = mt * 16 + (lane & 15);
        int kb   = s * 32 + ((lane >> 4) & 3) * 8;
        uint32_t pv[4];
#pragma unroll
        for (int jj = 0; jj < 4; ++jj) {
            float lo, hi;
            {
                int kk = kb + 2 * jj;
                int tp = kk >> 7, c = kk & 127;
                lo = w[(m * C_IN + c) * KTAP + tp];
            }
            {
                int kk = kb + 2 * jj + 1;
                int tp = kk >> 7, c = kk & 127;
                hi = w[(m * C_IN + c) * KTAP + tp];
            }
            pv[jj] = pkbf(lo, hi);
        }
        uint4 val; val.x = pv[0]; val.y = pv[1]; val.z = pv[2]; val.w = pv[3];
        *(uint4*)(wp + (size_t)tid * 8) = val;
        return;
    }

    // ---------------- transpose role ----------------
    __shared__ uint32_t ld[64][65];     // [e_local][c_pair], 16.64 KB

    const int b  = bid / TP_X;
    const int e0 = (bid % TP_X) * 64;
    const bool full = (e0 + 64 <= E_N);

    // load + convert: 4 double-passes; thread owns rows (c, c+1), 4 e's
#pragma unroll
    for (int dp = 0; dp < 4; ++dp) {
        const int c  = dp * 32 + (t >> 4) * 2;
        const int eo = (t & 15) * 4;
        float4 v0, v1;
        if (full) {
            v0 = *(const float4*)(x + ((size_t)(b * C_IN + c    ) * E_N + e0 + eo));
            v1 = *(const float4*)(x + ((size_t)(b * C_IN + c + 1) * E_N + e0 + eo));
        } else {
            float t0[4], t1[4];
            for (int i = 0; i < 4; ++i) {
                int e = e0 + eo + i;
                t0[i] = (e < E_N) ? x[(size_t)(b * C_IN + c    ) * E_N + e] : 0.f;
                t1[i] = (e < E_N) ? x[(size_t)(b * C_IN + c + 1) * E_N + e] : 0.f;
            }
            v0 = make_float4(t0[0], t0[1], t0[2], t0[3]);
            v1 = make_float4(t1[0], t1[1], t1[2], t1[3]);
        }
        const int cell = dp * 16 + (t >> 4);
        ld[eo + 0][cell] = pkbf(v0.x, v1.x);
        ld[eo + 1][cell] = pkbf(v0.y, v1.y);
        ld[eo + 2][cell] = pkbf(v0.z, v1.z);
        ld[eo + 3][cell] = pkbf(v0.w, v1.w);
    }
    __syncthreads();

    // store: thread writes 16 B (8 channels) of one edge row per pass
#pragma unroll
    for (int pass = 0; pass < 4; ++pass) {
        const int el = pass * 16 + (t >> 4);
        const int c4 = (t & 15) * 4;               // u32-cell index (8 halfwords)
        const int e  = e0 + el;
        if (e < E_N) {
            uint4 v;
            v.x = ld[el][c4 + 0];
            v.y = ld[el][c4 + 1];
            v.z = ld[el][c4 + 2];
            v.w = ld[el][c4 + 3];
            *(uint4*)(xT + (size_t)(b * E_N + e) * C_IN + c4 * 2) = v;
        }
    }
}

// ---------------------------------------------------------------------------
// Fused gather + tap-combine + GEMM, batch-pair software pipeline.
// EXACT round-5 body (passed, mesh <=77 us): round-0 structure with the
// three __syncthreads() replaced by LDS-only barriers (no vmcnt(0) drain).
// ---------------------------------------------------------------------------
__launch_bounds__(512, 4)
__global__ void mesh_gemm(const unsigned short* __restrict__ wp,
                          const unsigned short* __restrict__ xT,
                          const int* __restrict__ ne,
                          const float* __restrict__ bias,
                          float* __restrict__ out) {
    __shared__ uint4 gbuf[KTAP][BN][16];   // 81,920 B (XOR-swizzled chunks)

    const int e0   = blockIdx.x * BN;
    const int tid  = threadIdx.x;
    const int lane = tid & 63;
    const int wave = tid >> 6;
    const int b0   = blockIdx.y * 2;
    const int b1   = b0 + 1;

    // gather role: 8 threads/edge, each owns chunks ci and ci+8
    const int col = tid >> 3;
    const int ci  = tid & 7;
    int eg = e0 + col; if (eg >= E_N) eg = E_N - 1;

    const int4 nb0 = *(const int4*)(ne + ((size_t)b0 * E_N + eg) * 4);
    const int4 nb1 = *(const int4*)(ne + ((size_t)b1 * E_N + eg) * 4);

    const int sw = col & 15;
    const int cl = ci ^ sw;
    const int ch = (ci + 8) ^ sw;

    // MFMA-role constants
    const uint4* wp16 = (const uint4*)wp;
    const int nl   = lane & 15;
    const int kq   = lane >> 4;
    const int quad = kq;

    // hoist bias
    float bvl[2][4];
#pragma unroll
    for (int mt = 0; mt < 2; ++mt)
#pragma unroll
        for (int r = 0; r < 4; ++r)
            bvl[mt][r] = bias[(wave * 2 + mt) * 16 + quad * 4 + r];

    // ---------------- gather helpers ----------------
    auto gather10 = [&](int b, const int4& nb, uint4* g) {
        const unsigned short* xb = xT + (size_t)b * E_N * C_IN;
        const uint4* r0 = (const uint4*)(xb + (size_t)eg   * C_IN) + ci;
        const uint4* r1 = (const uint4*)(xb + (size_t)nb.x * C_IN) + ci;
        const uint4* r2 = (const uint4*)(xb + (size_t)nb.y * C_IN) + ci;
        const uint4* r3 = (const uint4*)(xb + (size_t)nb.z * C_IN) + ci;
        const uint4* r4 = (const uint4*)(xb + (size_t)nb.w * C_IN) + ci;
        g[0] = r0[0]; g[1] = r1[0]; g[2] = r2[0]; g[3] = r3[0]; g[4] = r4[0];
        g[5] = r0[8]; g[6] = r1[8]; g[7] = r2[8]; g[8] = r3[8]; g[9] = r4[8];
    };
    auto combineStore = [&](uint4* g) {
        uint4 s, d;
        gbuf[0][col][cl] = g[0];
        comb8(g[1], g[3], s, d); gbuf[1][col][cl] = s; gbuf[3][col][cl] = d;
        comb8(g[2], g[4], s, d); gbuf[2][col][cl] = s; gbuf[4][col][cl] = d;
        gbuf[0][col][ch] = g[5];
        comb8(g[6], g[8], s, d); gbuf[1][col][ch] = s; gbuf[3][col][ch] = d;
        comb8(g[7], g[9], s, d); gbuf[2][col][ch] = s; gbuf[4][col][ch] = d;
    };
    auto mfmaStore = [&](int b) {
        f32x4 acc[2][4];
#pragma unroll
        for (int mt = 0; mt < 2; ++mt)
#pragma unroll
            for (int nt = 0; nt < 4; ++nt)
                acc[mt][nt] = (f32x4){0.f, 0.f, 0.f, 0.f};
#pragma unroll 4
        for (int s = 0; s < 20; ++s) {
            const int tap = s >> 2, cbi = s & 3;
            uint4 w0 = wp16[(s * 16 + wave * 2 + 0) * 64 + lane];
            uint4 w1 = wp16[(s * 16 + wave * 2 + 1) * 64 + lane];
            bf16x8 af0 = *(bf16x8*)&w0;
            bf16x8 af1 = *(bf16x8*)&w1;
#pragma unroll
            for (int nt = 0; nt < 4; ++nt) {
                uint4 bv = gbuf[tap][nt * 16 + nl][((cbi << 2) + kq) ^ nl];
                bf16x8 bf = *(bf16x8*)&bv;
                acc[0][nt] = __builtin_amdgcn_mfma_f32_16x16x32_bf16(af0, bf, acc[0][nt], 0, 0, 0);
                acc[1][nt] = __builtin_amdgcn_mfma_f32_16x16x32_bf16(af1, bf, acc[1][nt], 0, 0, 0);
            }
        }
        // epilogue: C/D col = lane&15, row = quad*4 + r
#pragma unroll
        for (int mt = 0; mt < 2; ++mt) {
            const int ob = (wave * 2 + mt) * 16 + quad * 4;
#pragma unroll
            for (int r = 0; r < 4; ++r) {
                const int o = ob + r;
                const float bv = bvl[mt][r];
#pragma unroll
                for (int nt = 0; nt < 4; ++nt) {
                    const int e = e0 + nt * 16 + nl;
                    if (e < E_N)
                        out[((size_t)(b * C_OUT + o)) * E_N + e] = acc[mt][nt][r] + bv;
                }
            }
        }
    };

    // ---------------- pipeline ----------------
    uint4 ga[10];
    gather10(b0, nb0, ga);
    combineStore(ga);
    ldsBarrier();                          // A0: G(b0) visible (no vm drain)

    uint4 gb[10];
    gather10(b1, nb1, gb);                 // in flight under MFMA(b0)
    mfmaStore(b0);

    ldsBarrier();                          // B0: G(b0) reads done (stores stay in flight)
    combineStore(gb);
    ldsBarrier();                          // A1: G(b1) visible
    mfmaStore(b1);
}

// ---------------------------------------------------------------------------
// Fallback (ws too small): direct fp32 compute, slow but correct.
// ---------------------------------------------------------------------------
__global__ void fallback_kernel(const float* __restrict__ x,
                                const int* __restrict__ ne,
                                const float* __restrict__ w,
                                const float* __restrict__ bias,
                                float* __restrict__ out) {
    size_t id = (size_t)blockIdx.x * blockDim.x + threadIdx.x;
    if (id >= (size_t)B_N * C_OUT * E_N) return;
    int e = (int)(id % E_N);
    int o = (int)((id / E_N) % C_OUT);
    int b = (int)(id / ((size_t)E_N * C_OUT));
    const int4 nb = *(const int4*)(ne + ((size_t)b * E_N + e) * 4);
    float acc = bias[o];
    for (int c = 0; c < C_IN; ++c) {
        const float* xb = x + (size_t)(b * C_IN + c) * E_N;
        float s0 = xb[e];
        float x1 = xb[nb.x], x2 = xb[nb.y], x3 = xb[nb.z], x4 = xb[nb.w];
        const float* wo = w + (size_t)(o * C_IN + c) * KTAP;
        acc += wo[0] * s0
             + wo[1] * (x1 + x3)
             + wo[2] * (x2 + x4)
             + wo[3] * fabsf(x1 - x3)
             + wo[4] * fabsf(x2 - x4);
    }
    out[id] = acc;
}

extern "C" void kernel_launch(void* const* d_in, const int* in_sizes, int n_in,
                              void* d_out, int out_size, void* d_ws, size_t ws_size,
                              hipStream_t stream) {
    const float* x      = (const float*)d_in[0];
    const int*   ne_idx = (const int*)d_in[1];
    const float* conv_w = (const float*)d_in[2];
    const float* conv_b = (const float*)d_in[3];
    float* out = (float*)d_out;

    const size_t xT_off = 512 * 1024;
    const size_t need   = xT_off + (size_t)B_N * E_N * C_IN * 2;  // ~31.2 MB

    if (ws_size < need) {
        size_t total = (size_t)B_N * C_OUT * E_N;
        int blocks = (int)((total + 255) / 256);
        fallback_kernel<<<blocks, 256, 0, stream>>>(x, ne_idx, conv_w, conv_b, out);
        return;
    }

    unsigned short* wp = (unsigned short*)d_ws;
    unsigned short* xT = (unsigned short*)((char*)d_ws + xT_off);

    prep_kernel<<<TP_X * B_N + 80, 256, 0, stream>>>(x, xT, conv_w, wp);
    dim3 gg((E_N + BN - 1) / BN, B_N / 2);
    mesh_gemm<<<gg, 512, 0, stream>>>(wp, xT, ne_idx, conv_b, out);
}